// Round 1
// baseline (300.062 us; speedup 1.0000x reference)
//
#include <hip/hip_runtime.h>

// GraphCoordinator: for each node row x[n, 0:128], sequentially (p = 0..15)
// test exact float equality vs last_updated_param[p] and replace the row with
// learnable_param[p] on a full-row match. Running (in-place) semantics are
// preserved by holding the row in registers and replaying the p-loop.
// batch (d_in[1]) does not affect the output.
//
// Memory-bound: 512 MB read + 512 MB write => ~163 us floor at 6.3 TB/s.

#define F_DIM 128
#define P_DIM 16

__global__ __launch_bounds__(256) void graph_coord_kernel(
    const float* __restrict__ x,
    const float* __restrict__ learn,
    const float* __restrict__ last,
    float* __restrict__ out,
    int n_rows)
{
    __shared__ float s_last[P_DIM * F_DIM];   // 8 KB
    __shared__ float s_learn[P_DIM * F_DIM];  // 8 KB
    for (int i = threadIdx.x; i < P_DIM * F_DIM; i += blockDim.x) {
        s_last[i]  = last[i];
        s_learn[i] = learn[i];
    }
    __syncthreads();

    const int lane = threadIdx.x & 63;
    const int half = lane >> 5;   // which of the wave's 2 rows this lane serves
    const int sl   = lane & 31;   // 32 lanes x float4 = 128 floats = one row
    const int wavesPerBlock = blockDim.x >> 6;
    const long long nWaves = (long long)gridDim.x * wavesPerBlock;
    const long long wave   = (long long)blockIdx.x * wavesPerBlock + (threadIdx.x >> 6);

    for (long long rowBase = wave * 2; rowBase < n_rows; rowBase += nWaves * 2) {
        const long long row = rowBase + half;
        const bool active = (row < (long long)n_rows);

        float4 v = make_float4(0.f, 0.f, 0.f, 0.f);
        if (active)
            v = *reinterpret_cast<const float4*>(&x[row * F_DIM + sl * 4]);

        #pragma unroll
        for (int p = 0; p < P_DIM; ++p) {
            const float4 lp =
                *reinterpret_cast<const float4*>(&s_last[p * F_DIM + sl * 4]);
            const bool eq = (v.x == lp.x) & (v.y == lp.y) &
                            (v.z == lp.z) & (v.w == lp.w);
            // 64-bit wave ballot; this row's 32 lanes occupy one half of it.
            const unsigned long long m = __ballot(eq);
            const unsigned int mh = (unsigned int)(m >> (half * 32));
            if (mh == 0xFFFFFFFFu) {
                v = *reinterpret_cast<const float4*>(&s_learn[p * F_DIM + sl * 4]);
            }
        }

        if (active)
            *reinterpret_cast<float4*>(&out[row * F_DIM + sl * 4]) = v;
    }
}

extern "C" void kernel_launch(void* const* d_in, const int* in_sizes, int n_in,
                              void* d_out, int out_size, void* d_ws, size_t ws_size,
                              hipStream_t stream) {
    // setup_inputs() order: x [N*F] f32, batch [N] i64 (unused),
    //                       learnable_param [P*F] f32, last_updated_param [P*F] f32
    const float* x     = (const float*)d_in[0];
    const float* learn = (const float*)d_in[2];
    const float* last  = (const float*)d_in[3];
    float*       out   = (float*)d_out;

    const int n_rows = in_sizes[0] / F_DIM;  // 1,000,000

    // Memory-bound: ~2048 blocks + grid-stride (256 CUs x 8 blocks/CU).
    const int block = 256;
    const int grid  = 2048;
    graph_coord_kernel<<<grid, block, 0, stream>>>(x, learn, last, out, n_rows);
}

// Round 3
// 209.437 us; speedup vs baseline: 1.4327x; 1.4327x over previous
//
#include <hip/hip_runtime.h>

// GraphCoordinator: out = x, except rows exactly equal to last_updated_param[p]
// (sequential running scan p=0..15) are replaced with learnable_param[p].
// Matches are ~16 of 1,000,000 rows, so:
//   K1: zero candidate counter in d_ws
//   K2: grid-stride float4 memcpy x->out; the lane holding a row's element 0
//       compares it against the 16 signatures last[p][0]; on a (rare) hit,
//       pushes the row index into a d_ws candidate list.
//   K3: tiny fixup: for each candidate row, replay the exact sequential
//       p-loop (running semantics, full-row bitwise equality) and rewrite
//       that row of out.
// Candidate set is a correct superset: a row can only be mutated mid-scan if
// it first matched some p, which requires an original element-0 signature hit.
// Memory floor: 512 MB read + 512 MB write ~= 163 us @ 6.3 TB/s.

#define F_DIM 128
#define P_DIM 16
#define CAND_CAP 8192

__global__ void init_counter_kernel(int* ws) {
    if (threadIdx.x == 0 && blockIdx.x == 0) ws[0] = 0;
}

__global__ __launch_bounds__(256) void copy_scan_kernel(
    const float* __restrict__ x,
    const float* __restrict__ last,
    float* __restrict__ out,
    int* __restrict__ ws,      // ws[0] = counter, ws[1..] = candidate rows
    int n_rows)
{
    // 16 signatures: last[p][0]. Uniform addresses -> scalar loads.
    float sig[P_DIM];
    #pragma unroll
    for (int p = 0; p < P_DIM; ++p) sig[p] = last[p * F_DIM];

    const int total4 = n_rows * (F_DIM / 4);           // 32M float4s
    const int stride = gridDim.x * blockDim.x;
    for (int i4 = blockIdx.x * blockDim.x + threadIdx.x; i4 < total4; i4 += stride) {
        const float4 v = *reinterpret_cast<const float4*>(x + (size_t)i4 * 4);

        // Does this float4 start a row? (element index i4*4 divisible by 128)
        if ((i4 & ((F_DIM / 4) - 1)) == 0) {
            bool any = false;
            #pragma unroll
            for (int p = 0; p < P_DIM; ++p) any |= (v.x == sig[p]);
            if (any) {
                const int slot = atomicAdd(ws, 1);
                if (slot < CAND_CAP) ws[1 + slot] = i4 / (F_DIM / 4);
            }
        }

        *reinterpret_cast<float4*>(out + (size_t)i4 * 4) = v;
    }
}

__global__ __launch_bounds__(256) void fixup_kernel(
    const float* __restrict__ x,
    const float* __restrict__ learn,
    const float* __restrict__ last,
    float* __restrict__ out,
    const int* __restrict__ ws)
{
    const int n_cand = min(ws[0], CAND_CAP);
    const int lane = threadIdx.x & 63;
    const int wave = threadIdx.x >> 6;               // 4 waves in this block
    const int n_waves = blockDim.x >> 6;

    for (int c = wave; c < n_cand; c += n_waves) {
        const int row = ws[1 + c];
        // Each lane holds elements lane and lane+64 of the row.
        float v0 = x[(size_t)row * F_DIM + lane];
        float v1 = x[(size_t)row * F_DIM + 64 + lane];

        for (int p = 0; p < P_DIM; ++p) {
            const float l0 = last[p * F_DIM + lane];
            const float l1 = last[p * F_DIM + 64 + lane];
            const bool eq = (v0 == l0) & (v1 == l1);
            if (__ballot(eq) == ~0ULL) {             // full-row bitwise match
                v0 = learn[p * F_DIM + lane];
                v1 = learn[p * F_DIM + 64 + lane];
            }
        }
        out[(size_t)row * F_DIM + lane]      = v0;
        out[(size_t)row * F_DIM + 64 + lane] = v1;
    }
}

extern "C" void kernel_launch(void* const* d_in, const int* in_sizes, int n_in,
                              void* d_out, int out_size, void* d_ws, size_t ws_size,
                              hipStream_t stream) {
    // setup_inputs() order: x [N*F] f32, batch [N] i64 (unused),
    //                       learnable_param [P*F] f32, last_updated_param [P*F] f32
    const float* x     = (const float*)d_in[0];
    const float* learn = (const float*)d_in[2];
    const float* last  = (const float*)d_in[3];
    float*       out   = (float*)d_out;
    int*         ws    = (int*)d_ws;

    const int n_rows = in_sizes[0] / F_DIM;  // 1,000,000

    init_counter_kernel<<<1, 64, 0, stream>>>(ws);
    copy_scan_kernel<<<2048, 256, 0, stream>>>(x, last, out, ws, n_rows);
    fixup_kernel<<<1, 256, 0, stream>>>(x, learn, last, out, ws);
}

// Round 5
// 187.448 us; speedup vs baseline: 1.6008x; 1.1173x over previous
//
#include <hip/hip_runtime.h>

// GraphCoordinator: out = x, except rows exactly equal to last_updated_param[p]
// (sequential running scan p=0..15) are replaced with learnable_param[p].
// Matches are ~16 of 1,000,000 rows:
//   K1: zero candidate counter in d_ws
//   K2: 4-deep unrolled non-temporal float4 memcpy x->out; lanes with
//       (tid&31)==0 hold a row's element 0 and compare it against the 16
//       signatures last[p][0]; on a (rare) hit, push row index to d_ws list.
//   K3: tiny fixup: replay the exact sequential p-loop (running semantics,
//       full-row bitwise equality) for candidate rows only, rewrite out.
// Candidate set is a correct superset: a row can only be mutated mid-scan if
// it first matched some p, which requires an original element-0 signature hit.
// Memory floor: 512 MB read + 512 MB write ~= 163 us @ 6.3 TB/s copy ceiling.

#define F_DIM 128
#define P_DIM 16
#define CAND_CAP 8192
#define UNROLL 4

// Native clang vector type: __builtin_nontemporal_* requires scalar or
// native-vector element pointers (HIP_vector_type float4 is rejected).
typedef float f32x4 __attribute__((ext_vector_type(4)));

__global__ void init_counter_kernel(int* ws) {
    if (threadIdx.x == 0 && blockIdx.x == 0) ws[0] = 0;
}

__global__ __launch_bounds__(256) void copy_scan_kernel(
    const float* __restrict__ x,
    const float* __restrict__ last,
    float* __restrict__ out,
    int* __restrict__ ws,      // ws[0] = counter, ws[1..] = candidate rows
    int n_rows)
{
    // 16 signatures: last[p][0]. Uniform addresses -> scalar loads.
    float sig[P_DIM];
    #pragma unroll
    for (int p = 0; p < P_DIM; ++p) sig[p] = last[p * F_DIM];

    const f32x4* __restrict__ src = reinterpret_cast<const f32x4*>(x);
    f32x4*       __restrict__ dst = reinterpret_cast<f32x4*>(out);

    const int tid     = threadIdx.x;
    const int total4  = n_rows * (F_DIM / 4);                 // 32M float4s
    const int chunk   = blockDim.x * UNROLL;                  // 1024 float4/block-iter
    const int gstride = chunk * gridDim.x;

    for (int base = blockIdx.x * chunk; base < total4; base += gstride) {
        const int i0 = base + tid;

        // Issue all UNROLL coalesced loads before any store (MLP).
        f32x4 v[UNROLL];
        #pragma unroll
        for (int m = 0; m < UNROLL; ++m) {
            const int i4 = i0 + m * 256;
            if (i4 < total4)
                v[m] = __builtin_nontemporal_load(&src[i4]);
        }

        // base and m*256 are multiples of 32 float4s (= one 128-float row),
        // so lane tid holds a row start iff (tid & 31) == 0 — wave-uniform
        // divergence structure, hoisted out of the m-loop.
        if ((tid & 31) == 0) {
            #pragma unroll
            for (int m = 0; m < UNROLL; ++m) {
                const int i4 = i0 + m * 256;
                if (i4 < total4) {
                    bool any = false;
                    #pragma unroll
                    for (int p = 0; p < P_DIM; ++p) any |= (v[m].x == sig[p]);
                    if (any) {
                        const int slot = atomicAdd(ws, 1);
                        if (slot < CAND_CAP) ws[1 + slot] = i4 >> 5;  // /32 -> row
                    }
                }
            }
        }

        #pragma unroll
        for (int m = 0; m < UNROLL; ++m) {
            const int i4 = i0 + m * 256;
            if (i4 < total4)
                __builtin_nontemporal_store(v[m], &dst[i4]);
        }
    }
}

__global__ __launch_bounds__(256) void fixup_kernel(
    const float* __restrict__ x,
    const float* __restrict__ learn,
    const float* __restrict__ last,
    float* __restrict__ out,
    const int* __restrict__ ws)
{
    const int n_cand = min(ws[0], CAND_CAP);
    const int lane = threadIdx.x & 63;
    const int wave = threadIdx.x >> 6;               // 4 waves in this block
    const int n_waves = blockDim.x >> 6;

    for (int c = wave; c < n_cand; c += n_waves) {
        const int row = ws[1 + c];
        // Each lane holds elements lane and lane+64 of the row.
        float v0 = x[(size_t)row * F_DIM + lane];
        float v1 = x[(size_t)row * F_DIM + 64 + lane];

        for (int p = 0; p < P_DIM; ++p) {
            const float l0 = last[p * F_DIM + lane];
            const float l1 = last[p * F_DIM + 64 + lane];
            const bool eq = (v0 == l0) & (v1 == l1);
            if (__ballot(eq) == ~0ULL) {             // full-row bitwise match
                v0 = learn[p * F_DIM + lane];
                v1 = learn[p * F_DIM + 64 + lane];
            }
        }
        out[(size_t)row * F_DIM + lane]      = v0;
        out[(size_t)row * F_DIM + 64 + lane] = v1;
    }
}

extern "C" void kernel_launch(void* const* d_in, const int* in_sizes, int n_in,
                              void* d_out, int out_size, void* d_ws, size_t ws_size,
                              hipStream_t stream) {
    // setup_inputs() order: x [N*F] f32, batch [N] i64 (unused),
    //                       learnable_param [P*F] f32, last_updated_param [P*F] f32
    const float* x     = (const float*)d_in[0];
    const float* learn = (const float*)d_in[2];
    const float* last  = (const float*)d_in[3];
    float*       out   = (float*)d_out;
    int*         ws    = (int*)d_ws;

    const int n_rows = in_sizes[0] / F_DIM;  // 1,000,000

    init_counter_kernel<<<1, 64, 0, stream>>>(ws);
    copy_scan_kernel<<<2048, 256, 0, stream>>>(x, last, out, ws, n_rows);
    fixup_kernel<<<1, 256, 0, stream>>>(x, learn, last, out, ws);
}

// Round 6
// 182.420 us; speedup vs baseline: 1.6449x; 1.0276x over previous
//
#include <hip/hip_runtime.h>

// GraphCoordinator: out = x, except rows exactly equal to last_updated_param[p]
// (sequential running scan p=0..15) are replaced with learnable_param[p].
// Matches are ~16 of 1,000,000 rows. Single fused kernel:
//   - grid-stride 4-deep non-temporal float4 memcpy x->out
//   - the lane holding a row's element 0 ((tid&31)==0) compares it against the
//     16 signatures last[p][0]; on a wave-level hit (__any, ~never taken) the
//     half-wave owning that row replays the exact sequential p-loop with
//     full-row 32-lane ballot equality, running semantics in registers.
// Candidate gating is a correct superset: a row can only be mutated mid-scan
// if it first matches some p, which requires an original element-0 sig hit.
// Memory floor: 512 MB read + 512 MB write ~= 163 us @ 6.3 TB/s copy ceiling.

#define F_DIM 128
#define P_DIM 16
#define UNROLL 4

// Native clang vector type: __builtin_nontemporal_* rejects HIP_vector_type.
typedef float f32x4 __attribute__((ext_vector_type(4)));

__global__ __launch_bounds__(256) void copy_fix_kernel(
    const float* __restrict__ x,
    const float* __restrict__ learn,
    const float* __restrict__ last,
    float* __restrict__ out,
    int n_rows)
{
    // 16 signatures: last[p][0]. Uniform addresses -> scalar loads.
    float sig[P_DIM];
    #pragma unroll
    for (int p = 0; p < P_DIM; ++p) sig[p] = last[p * F_DIM];

    const f32x4* __restrict__ src = reinterpret_cast<const f32x4*>(x);
    f32x4*       __restrict__ dst = reinterpret_cast<f32x4*>(out);

    const int tid  = threadIdx.x;
    const int half = (tid >> 5) & 1;   // which half of the wave (row owner)
    const int sl   = tid & 31;         // float4 slot within the row

    const int total4  = n_rows * (F_DIM / 4);        // 32M float4s
    const int chunk   = 256 * UNROLL;                // 1024 float4 per block-iter
    const int gstride = chunk * gridDim.x;
    const int total4_full = total4 & ~(chunk - 1);   // guard-free region

    int base = blockIdx.x * chunk;
    for (; base < total4_full; base += gstride) {
        const int i0 = base + tid;

        // Issue all UNROLL coalesced loads before any store (MLP).
        f32x4 v[UNROLL];
        #pragma unroll
        for (int m = 0; m < UNROLL; ++m)
            v[m] = __builtin_nontemporal_load(&src[i0 + m * 256]);

        // Row-start lanes (sl==0) check element 0 against the 16 signatures.
        #pragma unroll
        for (int m = 0; m < UNROLL; ++m) {
            bool hit = false;
            if (sl == 0) {
                #pragma unroll
                for (int p = 0; p < P_DIM; ++p) hit |= (v[m].x == sig[p]);
            }
            if (__any(hit)) {
                // Cold path (~16 waves total across the whole grid): exact
                // sequential running-semantics replay for this wave's 2 rows.
                for (int p = 0; p < P_DIM; ++p) {
                    const f32x4 lp =
                        *reinterpret_cast<const f32x4*>(&last[p * F_DIM + sl * 4]);
                    const bool eq = (v[m].x == lp.x) & (v[m].y == lp.y) &
                                    (v[m].z == lp.z) & (v[m].w == lp.w);
                    const unsigned long long bm = __ballot(eq);
                    const unsigned int mh = (unsigned int)(bm >> (half * 32));
                    if (mh == 0xFFFFFFFFu)
                        v[m] = *reinterpret_cast<const f32x4*>(
                                   &learn[p * F_DIM + sl * 4]);
                }
            }
        }

        #pragma unroll
        for (int m = 0; m < UNROLL; ++m)
            __builtin_nontemporal_store(v[m], &dst[i0 + m * 256]);
    }

    // Guarded tail (empty when total4 % chunk == 0, as for N=1M).
    for (; base < total4; base += gstride) {
        const int i0 = base + tid;
        #pragma unroll
        for (int m = 0; m < UNROLL; ++m) {
            const int i4 = i0 + m * 256;
            if (i4 >= total4) continue;
            f32x4 v = __builtin_nontemporal_load(&src[i4]);
            bool hit = false;
            if (sl == 0) {
                #pragma unroll
                for (int p = 0; p < P_DIM; ++p) hit |= (v.x == sig[p]);
            }
            if (__any(hit)) {
                for (int p = 0; p < P_DIM; ++p) {
                    const f32x4 lp =
                        *reinterpret_cast<const f32x4*>(&last[p * F_DIM + sl * 4]);
                    const bool eq = (v.x == lp.x) & (v.y == lp.y) &
                                    (v.z == lp.z) & (v.w == lp.w);
                    const unsigned long long bm = __ballot(eq);
                    const unsigned int mh = (unsigned int)(bm >> (half * 32));
                    if (mh == 0xFFFFFFFFu)
                        v = *reinterpret_cast<const f32x4*>(
                                &learn[p * F_DIM + sl * 4]);
                }
            }
            __builtin_nontemporal_store(v, &dst[i4]);
        }
    }
}

extern "C" void kernel_launch(void* const* d_in, const int* in_sizes, int n_in,
                              void* d_out, int out_size, void* d_ws, size_t ws_size,
                              hipStream_t stream) {
    // setup_inputs() order: x [N*F] f32, batch [N] i64 (unused),
    //                       learnable_param [P*F] f32, last_updated_param [P*F] f32
    const float* x     = (const float*)d_in[0];
    const float* learn = (const float*)d_in[2];
    const float* last  = (const float*)d_in[3];
    float*       out   = (float*)d_out;

    const int n_rows = in_sizes[0] / F_DIM;  // 1,000,000

    copy_fix_kernel<<<2048, 256, 0, stream>>>(x, learn, last, out, n_rows);
}